// Round 1
// baseline (2196.760 us; speedup 1.0000x reference)
//
#include <hip/hip_runtime.h>
#include <cstdint>
#include <cstddef>

// Problem constants (B=2,S=2048 -> T=4096; D=1024; H=4096; E=8; top-k=2)
#define T_TOK 4096
#define DIM   1024
#define HID   4096
#define NE    8
#define PADMAX 8704   // 8192 pairs + 8*64 worst-case padding

__device__ __forceinline__ float silu_f(float v) {
  return v / (1.0f + expf(-v));
}

// ---------------------------------------------------------------- reset
__global__ void k_reset(float* prob_sum, unsigned* cnt, unsigned* cursor,
                        int* pair_tok, float* pair_wt) {
  int i = blockIdx.x * 256 + threadIdx.x;
  if (i < PADMAX) { pair_tok[i] = 0; pair_wt[i] = 0.0f; }
  if (i < NE) { prob_sum[i] = 0.0f; cnt[i] = 0u; cursor[i] = 0u; }
}

// ---------------------------------------------------------------- router
// 256 threads = 4 waves; each wave handles 4 tokens sequentially.
__global__ __launch_bounds__(256) void k_router(
    const float* __restrict__ x, const float* __restrict__ Wg,
    int* __restrict__ top_i, float* __restrict__ top_w,
    float* __restrict__ prob_sum, unsigned* __restrict__ cnt) {
  __shared__ float sWg[NE * DIM];      // 32 KB
  __shared__ float sProb[NE];
  __shared__ unsigned sCnt[NE];
  int tid = threadIdx.x;
  if (tid < NE) { sProb[tid] = 0.0f; sCnt[tid] = 0u; }
  for (int i = tid; i < NE * DIM; i += 256) sWg[i] = Wg[i];
  __syncthreads();

  int wave = tid >> 6, lane = tid & 63;
  for (int it = 0; it < 4; ++it) {
    int t = blockIdx.x * 16 + wave * 4 + it;
    const float* xp = x + (size_t)t * DIM;
    float acc[NE];
#pragma unroll
    for (int e = 0; e < NE; ++e) acc[e] = 0.0f;
    for (int i = 0; i < DIM / 64; ++i) {
      int d = i * 64 + lane;            // coalesced x, 2-way (free) LDS banks
      float xd = xp[d];
#pragma unroll
      for (int e = 0; e < NE; ++e) acc[e] = fmaf(xd, sWg[e * DIM + d], acc[e]);
    }
#pragma unroll
    for (int off = 32; off > 0; off >>= 1)
#pragma unroll
      for (int e = 0; e < NE; ++e) acc[e] += __shfl_xor(acc[e], off, 64);

    if (lane == 0) {
      // softmax over 8 logits
      float m = acc[0];
#pragma unroll
      for (int e = 1; e < NE; ++e) m = fmaxf(m, acc[e]);
      float pr[NE]; float s = 0.0f;
#pragma unroll
      for (int e = 0; e < NE; ++e) { pr[e] = expf(acc[e] - m); s += pr[e]; }
      float inv = 1.0f / s;
#pragma unroll
      for (int e = 0; e < NE; ++e) pr[e] *= inv;
      // top-2, ties -> lower index (matches lax.top_k)
      int i0 = 0; float v0 = pr[0];
#pragma unroll
      for (int e = 1; e < NE; ++e) if (pr[e] > v0) { v0 = pr[e]; i0 = e; }
      int i1 = -1; float v1 = -1.0f;
#pragma unroll
      for (int e = 0; e < NE; ++e) if (e != i0 && pr[e] > v1) { v1 = pr[e]; i1 = e; }
      float wn = 1.0f / (v0 + v1);
      top_i[t * 2 + 0] = i0; top_i[t * 2 + 1] = i1;
      top_w[t * 2 + 0] = v0 * wn; top_w[t * 2 + 1] = v1 * wn;
#pragma unroll
      for (int e = 0; e < NE; ++e) atomicAdd(&sProb[e], pr[e]);
      atomicAdd(&sCnt[i0], 1u);
      atomicAdd(&sCnt[i1], 1u);
    }
  }
  __syncthreads();
  if (tid < NE) {
    atomicAdd(&prob_sum[tid], sProb[tid]);
    atomicAdd(&cnt[tid], sCnt[tid]);
  }
}

// ---------------------------------------------------------------- scan + aux loss
__global__ void k_scan(const unsigned* __restrict__ cnt,
                       const float* __restrict__ prob_sum,
                       int* __restrict__ pad_off, int* __restrict__ ptotal,
                       float* __restrict__ aux_out) {
  if (threadIdx.x == 0 && blockIdx.x == 0) {
    int off = 0; float aux = 0.0f;
    for (int e = 0; e < NE; ++e) {
      pad_off[e] = off;
      off += (int)((cnt[e] + 63u) & ~63u);
      aux += ((float)cnt[e] / (float)T_TOK) * (prob_sum[e] / (float)T_TOK);
    }
    pad_off[NE] = off;
    *ptotal = off;
    *aux_out = (float)NE * aux;
  }
}

// ---------------------------------------------------------------- scatter pairs
__global__ void k_scatter(const int* __restrict__ top_i, const float* __restrict__ top_w,
                          const int* __restrict__ pad_off, unsigned* __restrict__ cursor,
                          int* __restrict__ pair_tok, float* __restrict__ pair_wt) {
  int t = blockIdx.x * 256 + threadIdx.x;
  if (t >= T_TOK) return;
#pragma unroll
  for (int k = 0; k < 2; ++k) {
    int e = top_i[t * 2 + k];
    unsigned pos = atomicAdd(&cursor[e], 1u);
    int idx = pad_off[e] + (int)pos;
    pair_tok[idx] = t;
    pair_wt[idx]  = top_w[t * 2 + k];
  }
}

// ---------------------------------------------------------------- out = w0*b2[e0] + w1*b2[e1]
__global__ void k_init_out(const int* __restrict__ top_i, const float* __restrict__ top_w,
                           const float* __restrict__ b2, float* __restrict__ out) {
  int idx = blockIdx.x * 256 + threadIdx.x;
  int t = idx >> 10, d = idx & (DIM - 1);
  int e0 = top_i[t * 2 + 0], e1 = top_i[t * 2 + 1];
  out[idx] = top_w[t * 2 + 0] * b2[e0 * DIM + d] + top_w[t * 2 + 1] * b2[e1 * DIM + d];
}

// ---------------------------------------------------------------- grouped GEMM1 + bias + SiLU
// h[p, j] = silu( x[tok(p)] . W1[e][:, j] + b1[e][j] ), columns [j0, j0+grid.x*64)
__global__ __launch_bounds__(256) void k_gemm1(
    const float* __restrict__ x, const float* __restrict__ W1,
    const float* __restrict__ b1, const int* __restrict__ pair_tok,
    const int* __restrict__ pad_off, const int* __restrict__ ptotal,
    float* __restrict__ h, int j0, int HcA) {
  int P = *ptotal;
  int p0 = blockIdx.y * 64;
  if (p0 >= P) return;
  int e = 0;
#pragma unroll
  for (int q = 1; q < NE; ++q) if (p0 >= pad_off[q]) e = q;

  __shared__ float As[16][68];   // transposed A, padded rows (16B-aligned, low conflict)
  __shared__ float Bs[16][64];
  __shared__ int sTok[64];
  int tid = threadIdx.x;
  if (tid < 64) sTok[tid] = pair_tok[p0 + tid];
  __syncthreads();

  int jt = j0 + blockIdx.x * 64;                 // global H column base
  int arow = tid >> 2, akq = (tid & 3) << 2;     // A tile loaders
  int bk = tid >> 4,  bj = (tid & 15) << 2;      // B tile loaders
  const float* xrow  = x + (size_t)sTok[arow] * DIM + akq;
  const float* Bbase = W1 + (size_t)e * DIM * HID + (size_t)bk * HID + jt + bj;

  int ty = tid >> 4, tx = tid & 15;              // 16x16 threads, 4x4 micro-tile
  float acc[4][4];
#pragma unroll
  for (int r = 0; r < 4; ++r)
#pragma unroll
    for (int c = 0; c < 4; ++c) acc[r][c] = 0.0f;

  for (int kt = 0; kt < DIM; kt += 16) {
    float4 av = *(const float4*)(xrow + kt);
    float4 bv = *(const float4*)(Bbase + (size_t)kt * HID);
    __syncthreads();
    As[akq + 0][arow] = av.x;
    As[akq + 1][arow] = av.y;
    As[akq + 2][arow] = av.z;
    As[akq + 3][arow] = av.w;
    *(float4*)&Bs[bk][bj] = bv;
    __syncthreads();
#pragma unroll
    for (int k = 0; k < 16; ++k) {
      float4 a = *(const float4*)&As[k][ty * 4];
      float4 b = *(const float4*)&Bs[k][tx * 4];
      acc[0][0] = fmaf(a.x, b.x, acc[0][0]); acc[0][1] = fmaf(a.x, b.y, acc[0][1]);
      acc[0][2] = fmaf(a.x, b.z, acc[0][2]); acc[0][3] = fmaf(a.x, b.w, acc[0][3]);
      acc[1][0] = fmaf(a.y, b.x, acc[1][0]); acc[1][1] = fmaf(a.y, b.y, acc[1][1]);
      acc[1][2] = fmaf(a.y, b.z, acc[1][2]); acc[1][3] = fmaf(a.y, b.w, acc[1][3]);
      acc[2][0] = fmaf(a.z, b.x, acc[2][0]); acc[2][1] = fmaf(a.z, b.y, acc[2][1]);
      acc[2][2] = fmaf(a.z, b.z, acc[2][2]); acc[2][3] = fmaf(a.z, b.w, acc[2][3]);
      acc[3][0] = fmaf(a.w, b.x, acc[3][0]); acc[3][1] = fmaf(a.w, b.y, acc[3][1]);
      acc[3][2] = fmaf(a.w, b.z, acc[3][2]); acc[3][3] = fmaf(a.w, b.w, acc[3][3]);
    }
  }

  float4 bias = *(const float4*)(b1 + (size_t)e * HID + jt + tx * 4);
  int lc = blockIdx.x * 64 + tx * 4;             // chunk-local column
#pragma unroll
  for (int r = 0; r < 4; ++r) {
    int row = ty * 4 + r;
    float4 o;
    o.x = silu_f(acc[r][0] + bias.x);
    o.y = silu_f(acc[r][1] + bias.y);
    o.z = silu_f(acc[r][2] + bias.z);
    o.w = silu_f(acc[r][3] + bias.w);
    *(float4*)&h[(size_t)(p0 + row) * HcA + lc] = o;
  }
}

// ---------------------------------------------------------------- grouped GEMM2 + weighted scatter-add
// out[tok(p), n] += w(p) * sum_k h[p, k] * W2[e][j0+k, n]
__global__ __launch_bounds__(256) void k_gemm2(
    const float* __restrict__ h, const float* __restrict__ W2,
    const int* __restrict__ pair_tok, const float* __restrict__ pair_wt,
    const int* __restrict__ pad_off, const int* __restrict__ ptotal,
    float* __restrict__ out, int j0, int Kc, int HcA) {
  int P = *ptotal;
  int p0 = blockIdx.y * 64;
  if (p0 >= P) return;
  int e = 0;
#pragma unroll
  for (int q = 1; q < NE; ++q) if (p0 >= pad_off[q]) e = q;

  __shared__ float As[16][68];
  __shared__ float Bs[16][64];
  int tid = threadIdx.x;

  int nt = blockIdx.x * 64;                      // output column base
  int arow = tid >> 2, akq = (tid & 3) << 2;
  int bk = tid >> 4,  bj = (tid & 15) << 2;
  const float* Arow  = h + (size_t)(p0 + arow) * HcA + akq;
  const float* Bbase = W2 + (size_t)e * HID * DIM + (size_t)(j0 + bk) * DIM + nt + bj;

  int ty = tid >> 4, tx = tid & 15;
  float acc[4][4];
#pragma unroll
  for (int r = 0; r < 4; ++r)
#pragma unroll
    for (int c = 0; c < 4; ++c) acc[r][c] = 0.0f;

  for (int kt = 0; kt < Kc; kt += 16) {
    float4 av = *(const float4*)(Arow + kt);
    float4 bv = *(const float4*)(Bbase + (size_t)kt * DIM);
    __syncthreads();
    As[akq + 0][arow] = av.x;
    As[akq + 1][arow] = av.y;
    As[akq + 2][arow] = av.z;
    As[akq + 3][arow] = av.w;
    *(float4*)&Bs[bk][bj] = bv;
    __syncthreads();
#pragma unroll
    for (int k = 0; k < 16; ++k) {
      float4 a = *(const float4*)&As[k][ty * 4];
      float4 b = *(const float4*)&Bs[k][tx * 4];
      acc[0][0] = fmaf(a.x, b.x, acc[0][0]); acc[0][1] = fmaf(a.x, b.y, acc[0][1]);
      acc[0][2] = fmaf(a.x, b.z, acc[0][2]); acc[0][3] = fmaf(a.x, b.w, acc[0][3]);
      acc[1][0] = fmaf(a.y, b.x, acc[1][0]); acc[1][1] = fmaf(a.y, b.y, acc[1][1]);
      acc[1][2] = fmaf(a.y, b.z, acc[1][2]); acc[1][3] = fmaf(a.y, b.w, acc[1][3]);
      acc[2][0] = fmaf(a.z, b.x, acc[2][0]); acc[2][1] = fmaf(a.z, b.y, acc[2][1]);
      acc[2][2] = fmaf(a.z, b.z, acc[2][2]); acc[2][3] = fmaf(a.z, b.w, acc[2][3]);
      acc[3][0] = fmaf(a.w, b.x, acc[3][0]); acc[3][1] = fmaf(a.w, b.y, acc[3][1]);
      acc[3][2] = fmaf(a.w, b.z, acc[3][2]); acc[3][3] = fmaf(a.w, b.w, acc[3][3]);
    }
  }

#pragma unroll
  for (int r = 0; r < 4; ++r) {
    int row = ty * 4 + r;
    float wt = pair_wt[p0 + row];
    if (wt != 0.0f) {
      int tok = pair_tok[p0 + row];
      float* op = out + (size_t)tok * DIM + nt + tx * 4;
      unsafeAtomicAdd(op + 0, wt * acc[r][0]);
      unsafeAtomicAdd(op + 1, wt * acc[r][1]);
      unsafeAtomicAdd(op + 2, wt * acc[r][2]);
      unsafeAtomicAdd(op + 3, wt * acc[r][3]);
    }
  }
}

// ---------------------------------------------------------------- launch
extern "C" void kernel_launch(void* const* d_in, const int* in_sizes, int n_in,
                              void* d_out, int out_size, void* d_ws, size_t ws_size,
                              hipStream_t stream) {
  const float* x  = (const float*)d_in[0];
  const float* Wg = (const float*)d_in[1];
  const float* W1 = (const float*)d_in[2];
  const float* b1 = (const float*)d_in[3];
  const float* W2 = (const float*)d_in[4];
  const float* b2 = (const float*)d_in[5];
  float* out = (float*)d_out;

  char* p = (char*)d_ws;
  auto alloc = [&](size_t bytes) -> char* {
    char* r = p; p += (bytes + 255) & ~(size_t)255; return r;
  };
  int*      top_i    = (int*)     alloc((size_t)T_TOK * 2 * sizeof(int));
  float*    top_w    = (float*)   alloc((size_t)T_TOK * 2 * sizeof(float));
  float*    prob_sum = (float*)   alloc(NE * sizeof(float));
  unsigned* cnt      = (unsigned*)alloc(NE * sizeof(unsigned));
  int*      pad_off  = (int*)     alloc((NE + 1) * sizeof(int));
  int*      ptotal   = (int*)     alloc(sizeof(int));
  unsigned* cursor   = (unsigned*)alloc(NE * sizeof(unsigned));
  int*      pair_tok = (int*)     alloc(PADMAX * sizeof(int));
  float*    pair_wt  = (float*)   alloc(PADMAX * sizeof(float));
  float*    hbuf     = (float*)   p;

  size_t used  = (size_t)((char*)hbuf - (char*)d_ws);
  size_t avail = ws_size > used ? ws_size - used : 0;
  size_t hc_max = avail / (sizeof(float) * (size_t)PADMAX);
  int Hc = (int)(hc_max & ~(size_t)63);
  if (Hc > HID) Hc = HID;
  if (Hc < 64)  Hc = 64;   // requires ~3.3 MB minimum workspace

  k_reset<<<dim3((PADMAX + 255) / 256), 256, 0, stream>>>(prob_sum, cnt, cursor, pair_tok, pair_wt);
  k_router<<<dim3(T_TOK / 16), 256, 0, stream>>>(x, Wg, top_i, top_w, prob_sum, cnt);
  k_scan<<<1, 64, 0, stream>>>(cnt, prob_sum, pad_off, ptotal, out + (size_t)T_TOK * DIM);
  k_scatter<<<dim3(T_TOK / 256), 256, 0, stream>>>(top_i, top_w, pad_off, cursor, pair_tok, pair_wt);
  k_init_out<<<dim3((size_t)T_TOK * DIM / 256), 256, 0, stream>>>(top_i, top_w, b2, out);

  for (int jb = 0; jb < HID; jb += Hc) {
    int hc = (HID - jb) < Hc ? (HID - jb) : Hc;
    k_gemm1<<<dim3(hc / 64, PADMAX / 64), 256, 0, stream>>>(
        x, W1, b1, pair_tok, pad_off, ptotal, hbuf, jb, Hc);
    k_gemm2<<<dim3(DIM / 64, PADMAX / 64), 256, 0, stream>>>(
        hbuf, W2, pair_tok, pair_wt, pad_off, ptotal, out, jb, hc, Hc);
  }
}

// Round 5
// 781.587 us; speedup vs baseline: 2.8106x; 2.8106x over previous
//
#include <hip/hip_runtime.h>
#include <cstdint>
#include <cstddef>

// Problem constants (B=2,S=2048 -> T=4096; D=1024; H=4096; E=8; top-k=2)
#define T_TOK 4096
#define DIM   1024
#define HID   4096
#define NE    8
#define PAD   128
#define PADMAX 9216   // sum_e ceil(cnt_e/128)*128 <= 8192 + 8*127 = 9208 -> 9216

typedef _Float16 half_t;
typedef __attribute__((ext_vector_type(8))) _Float16 half8;
typedef __attribute__((ext_vector_type(4))) float floatx4;

__device__ __forceinline__ float silu_f(float v) {
  return v / (1.0f + expf(-v));
}

__device__ __forceinline__ half8 cvt44(float4 a, float4 b) {
  half8 o;
  o[0] = (half_t)a.x; o[1] = (half_t)a.y; o[2] = (half_t)a.z; o[3] = (half_t)a.w;
  o[4] = (half_t)b.x; o[5] = (half_t)b.y; o[6] = (half_t)b.z; o[7] = (half_t)b.w;
  return o;
}

// ---------------------------------------------------------------- reset
__global__ void k_reset(float* prob_sum, unsigned* cnt, unsigned* cursor,
                        int* pair_tok, float* pair_wt) {
  int i = blockIdx.x * 256 + threadIdx.x;
  if (i < PADMAX) { pair_tok[i] = 0; pair_wt[i] = 0.0f; }
  if (i < NE) { prob_sum[i] = 0.0f; cnt[i] = 0u; cursor[i] = 0u; }
}

// ---------------------------------------------------------------- W1 [E][D][H] -> W1t [E][Hc][D] f16
__global__ __launch_bounds__(256) void k_tr_w1(const float* __restrict__ W1,
                                               half_t* __restrict__ W1t,
                                               int j0, int Hc) {
  __shared__ half_t T[64][72];
  int e = blockIdx.z, h0 = blockIdx.x * 64, d0 = blockIdx.y * 64;
  int tid = threadIdx.x;
  {
    int r = tid >> 2, c16 = (tid & 3) * 16;
    const float* s = W1 + ((size_t)e * DIM + d0 + r) * HID + j0 + h0 + c16;
    float4 a = ((const float4*)s)[0], b = ((const float4*)s)[1];
    float4 c = ((const float4*)s)[2], d = ((const float4*)s)[3];
    *(half8*)&T[r][c16] = cvt44(a, b);
    *(half8*)&T[r][c16 + 8] = cvt44(c, d);
  }
  __syncthreads();
  {
    int n = tid >> 2, d16 = (tid & 3) * 16;
    half8 u, v;
#pragma unroll
    for (int j = 0; j < 8; ++j) { u[j] = T[d16 + j][n]; v[j] = T[d16 + 8 + j][n]; }
    half_t* dst = W1t + ((size_t)e * Hc + h0 + n) * DIM + d0 + d16;
    *(half8*)dst = u;
    *(half8*)(dst + 8) = v;
  }
}

// ---------------------------------------------------------------- W2 [E][H][D] -> W2t [E][D][Hc] f16
__global__ __launch_bounds__(256) void k_tr_w2(const float* __restrict__ W2,
                                               half_t* __restrict__ W2t,
                                               int j0, int Hc) {
  __shared__ half_t T[64][72];
  int e = blockIdx.z, d0 = blockIdx.x * 64, h0 = blockIdx.y * 64;
  int tid = threadIdx.x;
  {
    int r = tid >> 2, c16 = (tid & 3) * 16;
    const float* s = W2 + ((size_t)e * HID + j0 + h0 + r) * DIM + d0 + c16;
    float4 a = ((const float4*)s)[0], b = ((const float4*)s)[1];
    float4 c = ((const float4*)s)[2], d = ((const float4*)s)[3];
    *(half8*)&T[r][c16] = cvt44(a, b);
    *(half8*)&T[r][c16 + 8] = cvt44(c, d);
  }
  __syncthreads();
  {
    int n = tid >> 2, h16 = (tid & 3) * 16;
    half8 u, v;
#pragma unroll
    for (int j = 0; j < 8; ++j) { u[j] = T[h16 + j][n]; v[j] = T[h16 + 8 + j][n]; }
    half_t* dst = W2t + ((size_t)e * DIM + d0 + n) * Hc + h0 + h16;
    *(half8*)dst = u;
    *(half8*)(dst + 8) = v;
  }
}

// ---------------------------------------------------------------- router
__global__ __launch_bounds__(256) void k_router(
    const float* __restrict__ x, const float* __restrict__ Wg,
    int* __restrict__ top_i, float* __restrict__ top_w,
    float* __restrict__ prob_sum, unsigned* __restrict__ cnt) {
  __shared__ float sWg[NE * DIM];
  __shared__ float sProb[NE];
  __shared__ unsigned sCnt[NE];
  int tid = threadIdx.x;
  if (tid < NE) { sProb[tid] = 0.0f; sCnt[tid] = 0u; }
  for (int i = tid; i < NE * DIM; i += 256) sWg[i] = Wg[i];
  __syncthreads();

  int wave = tid >> 6, lane = tid & 63;
  for (int it = 0; it < 4; ++it) {
    int t = blockIdx.x * 16 + wave * 4 + it;
    const float* xp = x + (size_t)t * DIM;
    float acc[NE];
#pragma unroll
    for (int e = 0; e < NE; ++e) acc[e] = 0.0f;
    for (int i = 0; i < DIM / 64; ++i) {
      int d = i * 64 + lane;
      float xd = xp[d];
#pragma unroll
      for (int e = 0; e < NE; ++e) acc[e] = fmaf(xd, sWg[e * DIM + d], acc[e]);
    }
#pragma unroll
    for (int off = 32; off > 0; off >>= 1)
#pragma unroll
      for (int e = 0; e < NE; ++e) acc[e] += __shfl_xor(acc[e], off, 64);

    if (lane == 0) {
      float m = acc[0];
#pragma unroll
      for (int e = 1; e < NE; ++e) m = fmaxf(m, acc[e]);
      float pr[NE]; float s = 0.0f;
#pragma unroll
      for (int e = 0; e < NE; ++e) { pr[e] = expf(acc[e] - m); s += pr[e]; }
      float inv = 1.0f / s;
#pragma unroll
      for (int e = 0; e < NE; ++e) pr[e] *= inv;
      int i0 = 0; float v0 = pr[0];
#pragma unroll
      for (int e = 1; e < NE; ++e) if (pr[e] > v0) { v0 = pr[e]; i0 = e; }
      int i1 = -1; float v1 = -1.0f;
#pragma unroll
      for (int e = 0; e < NE; ++e) if (e != i0 && pr[e] > v1) { v1 = pr[e]; i1 = e; }
      float wn = 1.0f / (v0 + v1);
      top_i[t * 2 + 0] = i0; top_i[t * 2 + 1] = i1;
      top_w[t * 2 + 0] = v0 * wn; top_w[t * 2 + 1] = v1 * wn;
#pragma unroll
      for (int e = 0; e < NE; ++e) atomicAdd(&sProb[e], pr[e]);
      atomicAdd(&sCnt[i0], 1u);
      atomicAdd(&sCnt[i1], 1u);
    }
  }
  __syncthreads();
  if (tid < NE) {
    atomicAdd(&prob_sum[tid], sProb[tid]);
    atomicAdd(&cnt[tid], sCnt[tid]);
  }
}

// ---------------------------------------------------------------- scan + aux loss
__global__ void k_scan(const unsigned* __restrict__ cnt,
                       const float* __restrict__ prob_sum,
                       int* __restrict__ pad_off, int* __restrict__ ptotal,
                       float* __restrict__ aux_out) {
  if (threadIdx.x == 0 && blockIdx.x == 0) {
    int off = 0; float aux = 0.0f;
    for (int e = 0; e < NE; ++e) {
      pad_off[e] = off;
      off += (int)((cnt[e] + (PAD - 1u)) & ~(unsigned)(PAD - 1));
      aux += ((float)cnt[e] / (float)T_TOK) * (prob_sum[e] / (float)T_TOK);
    }
    pad_off[NE] = off;
    *ptotal = off;
    *aux_out = (float)NE * aux;
  }
}

// ---------------------------------------------------------------- scatter pairs
__global__ void k_scatter(const int* __restrict__ top_i, const float* __restrict__ top_w,
                          const int* __restrict__ pad_off, unsigned* __restrict__ cursor,
                          int* __restrict__ pair_tok, float* __restrict__ pair_wt) {
  int t = blockIdx.x * 256 + threadIdx.x;
  if (t >= T_TOK) return;
#pragma unroll
  for (int k = 0; k < 2; ++k) {
    int e = top_i[t * 2 + k];
    unsigned pos = atomicAdd(&cursor[e], 1u);
    int idx = pad_off[e] + (int)pos;
    pair_tok[idx] = t;
    pair_wt[idx]  = top_w[t * 2 + k];
  }
}

// ---------------------------------------------------------------- out = w0*b2[e0] + w1*b2[e1]
__global__ void k_init_out(const int* __restrict__ top_i, const float* __restrict__ top_w,
                           const float* __restrict__ b2, float* __restrict__ out) {
  int idx = blockIdx.x * 256 + threadIdx.x;
  int t = idx >> 10, d = idx & (DIM - 1);
  int e0 = top_i[t * 2 + 0], e1 = top_i[t * 2 + 1];
  out[idx] = top_w[t * 2 + 0] * b2[e0 * DIM + d] + top_w[t * 2 + 1] * b2[e1 * DIM + d];
}

// ================================================================ Mode A GEMM1 (f16 transposed weights)
__global__ __launch_bounds__(256) void k_gemm1_a(
    const float* __restrict__ x, const half_t* __restrict__ W1t,
    const float* __restrict__ b1, const int* __restrict__ pair_tok,
    const int* __restrict__ pad_off, const int* __restrict__ ptotal,
    half_t* __restrict__ hout, int j0, int Hc) {
  __shared__ half_t lds[16384];
  int P = *ptotal;
  int p0 = blockIdx.y * 128;
  if (p0 >= P) return;
  int e = 0;
#pragma unroll
  for (int q = 1; q < NE; ++q) if (p0 >= pad_off[q]) e = q;

  int tid = threadIdx.x, w = tid >> 6, l = tid & 63;
  int lr = l & 15, lq = l >> 4;
  int wr = w >> 1, wc = w & 1;
  int jt = blockIdx.x * 128;

  int tok0 = pair_tok[p0 + (2 * w) * 16 + lr];
  int tok1 = pair_tok[p0 + (2 * w + 1) * 16 + lr];
  const float* gA0 = x + (size_t)tok0 * DIM + lq * 8;
  const float* gA1 = x + (size_t)tok1 * DIM + lq * 8;
  const half_t* gB0 = W1t + ((size_t)e * Hc + jt + (2 * w) * 16 + lr) * DIM + lq * 8;
  const half_t* gB1 = W1t + ((size_t)e * Hc + jt + (2 * w + 1) * 16 + lr) * DIM + lq * 8;

  half_t* ldsA = lds;
  half_t* ldsB = lds + 8192;

  floatx4 acc[4][4];
#pragma unroll
  for (int i = 0; i < 4; ++i)
#pragma unroll
    for (int j = 0; j < 4; ++j) acc[i][j] = (floatx4){0.f, 0.f, 0.f, 0.f};

  for (int kt = 0; kt < DIM; kt += 64) {
    half8 va0 = cvt44(*(const float4*)(gA0 + kt),      *(const float4*)(gA0 + kt + 4));
    half8 va1 = cvt44(*(const float4*)(gA0 + kt + 32), *(const float4*)(gA0 + kt + 36));
    half8 va2 = cvt44(*(const float4*)(gA1 + kt),      *(const float4*)(gA1 + kt + 4));
    half8 va3 = cvt44(*(const float4*)(gA1 + kt + 32), *(const float4*)(gA1 + kt + 36));
    half8 vb0 = *(const half8*)(gB0 + kt);
    half8 vb1 = *(const half8*)(gB0 + kt + 32);
    half8 vb2 = *(const half8*)(gB1 + kt);
    half8 vb3 = *(const half8*)(gB1 + kt + 32);
    __syncthreads();
    *(half8*)(ldsA + (4 * w + 0) * 512 + l * 8) = va0;
    *(half8*)(ldsA + (4 * w + 1) * 512 + l * 8) = va1;
    *(half8*)(ldsA + (4 * w + 2) * 512 + l * 8) = va2;
    *(half8*)(ldsA + (4 * w + 3) * 512 + l * 8) = va3;
    *(half8*)(ldsB + (4 * w + 0) * 512 + l * 8) = vb0;
    *(half8*)(ldsB + (4 * w + 1) * 512 + l * 8) = vb1;
    *(half8*)(ldsB + (4 * w + 2) * 512 + l * 8) = vb2;
    *(half8*)(ldsB + (4 * w + 3) * 512 + l * 8) = vb3;
    __syncthreads();
#pragma unroll
    for (int ks = 0; ks < 2; ++ks) {
      half8 a[4], b[4];
#pragma unroll
      for (int i = 0; i < 4; ++i)
        a[i] = *(const half8*)(ldsA + ((4 * wr + i) * 2 + ks) * 512 + l * 8);
#pragma unroll
      for (int j = 0; j < 4; ++j)
        b[j] = *(const half8*)(ldsB + ((4 * wc + j) * 2 + ks) * 512 + l * 8);
#pragma unroll
      for (int i = 0; i < 4; ++i)
#pragma unroll
        for (int j = 0; j < 4; ++j)
          acc[i][j] = __builtin_amdgcn_mfma_f32_16x16x32_f16(a[i], b[j], acc[i][j], 0, 0, 0);
    }
  }
  __syncthreads();

#pragma unroll
  for (int j = 0; j < 4; ++j) {
    int coll = (4 * wc + j) * 16 + lr;
    float bias = b1[(size_t)e * HID + j0 + jt + coll];
#pragma unroll
    for (int i = 0; i < 4; ++i)
#pragma unroll
      for (int r = 0; r < 4; ++r) {
        int row = (4 * wr + i) * 16 + lq * 4 + r;
        lds[row * 128 + coll] = (half_t)silu_f(acc[i][j][r] + bias);
      }
  }
  __syncthreads();
  // FIXED: each thread stores 16 halves (two half8) to cover all 128 columns.
#pragma unroll
  for (int ps = 0; ps < 4; ++ps) {
    int r = ps * 32 + (tid >> 3), c = (tid & 7) * 16;
    half8 v0 = *(const half8*)(lds + r * 128 + c);
    half8 v1 = *(const half8*)(lds + r * 128 + c + 8);
    half_t* dst = hout + (size_t)(p0 + r) * Hc + jt + c;
    *(half8*)dst = v0;
    *(half8*)(dst + 8) = v1;
  }
}

// ================================================================ Mode A GEMM2
__global__ __launch_bounds__(256) void k_gemm2_a(
    const half_t* __restrict__ hbuf, const half_t* __restrict__ W2t,
    const int* __restrict__ pair_tok, const float* __restrict__ pair_wt,
    const int* __restrict__ pad_off, const int* __restrict__ ptotal,
    float* __restrict__ out, int Hc) {
  __shared__ half_t lds[16384];
  int P = *ptotal;
  int p0 = blockIdx.y * 128;
  if (p0 >= P) return;
  int e = 0;
#pragma unroll
  for (int q = 1; q < NE; ++q) if (p0 >= pad_off[q]) e = q;

  int tid = threadIdx.x, w = tid >> 6, l = tid & 63;
  int lr = l & 15, lq = l >> 4;
  int wr = w >> 1, wc = w & 1;
  int jt = blockIdx.x * 128;

  const half_t* gA0 = hbuf + (size_t)(p0 + (2 * w) * 16 + lr) * Hc + lq * 8;
  const half_t* gA1 = hbuf + (size_t)(p0 + (2 * w + 1) * 16 + lr) * Hc + lq * 8;
  const half_t* gB0 = W2t + ((size_t)e * DIM + jt + (2 * w) * 16 + lr) * Hc + lq * 8;
  const half_t* gB1 = W2t + ((size_t)e * DIM + jt + (2 * w + 1) * 16 + lr) * Hc + lq * 8;

  half_t* ldsA = lds;
  half_t* ldsB = lds + 8192;

  floatx4 acc[4][4];
#pragma unroll
  for (int i = 0; i < 4; ++i)
#pragma unroll
    for (int j = 0; j < 4; ++j) acc[i][j] = (floatx4){0.f, 0.f, 0.f, 0.f};

  for (int kt = 0; kt < Hc; kt += 64) {
    half8 va0 = *(const half8*)(gA0 + kt);
    half8 va1 = *(const half8*)(gA0 + kt + 32);
    half8 va2 = *(const half8*)(gA1 + kt);
    half8 va3 = *(const half8*)(gA1 + kt + 32);
    half8 vb0 = *(const half8*)(gB0 + kt);
    half8 vb1 = *(const half8*)(gB0 + kt + 32);
    half8 vb2 = *(const half8*)(gB1 + kt);
    half8 vb3 = *(const half8*)(gB1 + kt + 32);
    __syncthreads();
    *(half8*)(ldsA + (4 * w + 0) * 512 + l * 8) = va0;
    *(half8*)(ldsA + (4 * w + 1) * 512 + l * 8) = va1;
    *(half8*)(ldsA + (4 * w + 2) * 512 + l * 8) = va2;
    *(half8*)(ldsA + (4 * w + 3) * 512 + l * 8) = va3;
    *(half8*)(ldsB + (4 * w + 0) * 512 + l * 8) = vb0;
    *(half8*)(ldsB + (4 * w + 1) * 512 + l * 8) = vb1;
    *(half8*)(ldsB + (4 * w + 2) * 512 + l * 8) = vb2;
    *(half8*)(ldsB + (4 * w + 3) * 512 + l * 8) = vb3;
    __syncthreads();
#pragma unroll
    for (int ks = 0; ks < 2; ++ks) {
      half8 a[4], b[4];
#pragma unroll
      for (int i = 0; i < 4; ++i)
        a[i] = *(const half8*)(ldsA + ((4 * wr + i) * 2 + ks) * 512 + l * 8);
#pragma unroll
      for (int j = 0; j < 4; ++j)
        b[j] = *(const half8*)(ldsB + ((4 * wc + j) * 2 + ks) * 512 + l * 8);
#pragma unroll
      for (int i = 0; i < 4; ++i)
#pragma unroll
        for (int j = 0; j < 4; ++j)
          acc[i][j] = __builtin_amdgcn_mfma_f32_16x16x32_f16(a[i], b[j], acc[i][j], 0, 0, 0);
    }
  }

#pragma unroll
  for (int i = 0; i < 4; ++i)
#pragma unroll
    for (int r = 0; r < 4; ++r) {
      int row = (4 * wr + i) * 16 + lq * 4 + r;
      float wt = pair_wt[p0 + row];
      if (wt != 0.0f) {
        int tok = pair_tok[p0 + row];
        float* op = out + (size_t)tok * DIM + jt;
#pragma unroll
        for (int j = 0; j < 4; ++j) {
          int coll = (4 * wc + j) * 16 + lr;
          unsafeAtomicAdd(op + coll, wt * acc[i][j][r]);
        }
      }
    }
}

// ================================================================ Mode B GEMM1 (fp32 weights direct)
__global__ __launch_bounds__(256) void k_gemm1_b(
    const float* __restrict__ x, const float* __restrict__ W1,
    const float* __restrict__ b1, const int* __restrict__ pair_tok,
    const int* __restrict__ pad_off, const int* __restrict__ ptotal,
    half_t* __restrict__ hout, int j0, int Hc) {
  __shared__ half_t lds[16384];
  int P = *ptotal;
  int p0 = blockIdx.y * 128;
  if (p0 >= P) return;
  int e = 0;
#pragma unroll
  for (int q = 1; q < NE; ++q) if (p0 >= pad_off[q]) e = q;

  int tid = threadIdx.x, w = tid >> 6, l = tid & 63;
  int lr = l & 15, lq = l >> 4;
  int wr = w >> 1, wc = w & 1;
  int jt = blockIdx.x * 128;

  int tok0 = pair_tok[p0 + (2 * w) * 16 + lr];
  int tok1 = pair_tok[p0 + (2 * w + 1) * 16 + lr];
  const float* gA0 = x + (size_t)tok0 * DIM + lq * 8;
  const float* gA1 = x + (size_t)tok1 * DIM + lq * 8;
  const float* gBb = W1 + (size_t)e * DIM * HID + j0 + jt;
  const float* gB0 = gBb + (2 * w) * 16 + lr;
  const float* gB1 = gBb + (2 * w + 1) * 16 + lr;

  half_t* ldsA = lds;
  half_t* ldsB = lds + 8192;

  floatx4 acc[4][4];
#pragma unroll
  for (int i = 0; i < 4; ++i)
#pragma unroll
    for (int j = 0; j < 4; ++j) acc[i][j] = (floatx4){0.f, 0.f, 0.f, 0.f};

  for (int kt = 0; kt < DIM; kt += 64) {
    half8 va0 = cvt44(*(const float4*)(gA0 + kt),      *(const float4*)(gA0 + kt + 4));
    half8 va1 = cvt44(*(const float4*)(gA0 + kt + 32), *(const float4*)(gA0 + kt + 36));
    half8 va2 = cvt44(*(const float4*)(gA1 + kt),      *(const float4*)(gA1 + kt + 4));
    half8 va3 = cvt44(*(const float4*)(gA1 + kt + 32), *(const float4*)(gA1 + kt + 36));
    half8 vb[4];
#pragma unroll
    for (int fg = 0; fg < 4; ++fg) {
      const float* gb = (fg >> 1) ? gB1 : gB0;
      int kbase = kt + (fg & 1) * 32 + lq * 8;
#pragma unroll
      for (int j = 0; j < 8; ++j)
        vb[fg][j] = (half_t)gb[(size_t)(kbase + j) * HID];
    }
    __syncthreads();
    *(half8*)(ldsA + (4 * w + 0) * 512 + l * 8) = va0;
    *(half8*)(ldsA + (4 * w + 1) * 512 + l * 8) = va1;
    *(half8*)(ldsA + (4 * w + 2) * 512 + l * 8) = va2;
    *(half8*)(ldsA + (4 * w + 3) * 512 + l * 8) = va3;
    *(half8*)(ldsB + (4 * w + 0) * 512 + l * 8) = vb[0];
    *(half8*)(ldsB + (4 * w + 1) * 512 + l * 8) = vb[1];
    *(half8*)(ldsB + (4 * w + 2) * 512 + l * 8) = vb[2];
    *(half8*)(ldsB + (4 * w + 3) * 512 + l * 8) = vb[3];
    __syncthreads();
#pragma unroll
    for (int ks = 0; ks < 2; ++ks) {
      half8 a[4], b[4];
#pragma unroll
      for (int i = 0; i < 4; ++i)
        a[i] = *(const half8*)(ldsA + ((4 * wr + i) * 2 + ks) * 512 + l * 8);
#pragma unroll
      for (int j = 0; j < 4; ++j)
        b[j] = *(const half8*)(ldsB + ((4 * wc + j) * 2 + ks) * 512 + l * 8);
#pragma unroll
      for (int i = 0; i < 4; ++i)
#pragma unroll
        for (int j = 0; j < 4; ++j)
          acc[i][j] = __builtin_amdgcn_mfma_f32_16x16x32_f16(a[i], b[j], acc[i][j], 0, 0, 0);
    }
  }
  __syncthreads();

#pragma unroll
  for (int j = 0; j < 4; ++j) {
    int coll = (4 * wc + j) * 16 + lr;
    float bias = b1[(size_t)e * HID + j0 + jt + coll];
#pragma unroll
    for (int i = 0; i < 4; ++i)
#pragma unroll
      for (int r = 0; r < 4; ++r) {
        int row = (4 * wr + i) * 16 + lq * 4 + r;
        lds[row * 128 + coll] = (half_t)silu_f(acc[i][j][r] + bias);
      }
  }
  __syncthreads();
  // FIXED: two half8 per thread.
#pragma unroll
  for (int ps = 0; ps < 4; ++ps) {
    int r = ps * 32 + (tid >> 3), c = (tid & 7) * 16;
    half8 v0 = *(const half8*)(lds + r * 128 + c);
    half8 v1 = *(const half8*)(lds + r * 128 + c + 8);
    half_t* dst = hout + (size_t)(p0 + r) * Hc + jt + c;
    *(half8*)dst = v0;
    *(half8*)(dst + 8) = v1;
  }
}

// ================================================================ Mode B GEMM2 (fp32 W2 direct)
__global__ __launch_bounds__(256) void k_gemm2_b(
    const half_t* __restrict__ hbuf, const float* __restrict__ W2,
    const int* __restrict__ pair_tok, const float* __restrict__ pair_wt,
    const int* __restrict__ pad_off, const int* __restrict__ ptotal,
    float* __restrict__ out, int j0, int Hc) {
  __shared__ half_t lds[16384];
  int P = *ptotal;
  int p0 = blockIdx.y * 128;
  if (p0 >= P) return;
  int e = 0;
#pragma unroll
  for (int q = 1; q < NE; ++q) if (p0 >= pad_off[q]) e = q;

  int tid = threadIdx.x, w = tid >> 6, l = tid & 63;
  int lr = l & 15, lq = l >> 4;
  int wr = w >> 1, wc = w & 1;
  int jt = blockIdx.x * 128;

  const half_t* gA0 = hbuf + (size_t)(p0 + (2 * w) * 16 + lr) * Hc + lq * 8;
  const half_t* gA1 = hbuf + (size_t)(p0 + (2 * w + 1) * 16 + lr) * Hc + lq * 8;
  const float* gBb = W2 + (size_t)e * HID * DIM + jt;
  const float* gB0 = gBb + (2 * w) * 16 + lr;
  const float* gB1 = gBb + (2 * w + 1) * 16 + lr;

  half_t* ldsA = lds;
  half_t* ldsB = lds + 8192;

  floatx4 acc[4][4];
#pragma unroll
  for (int i = 0; i < 4; ++i)
#pragma unroll
    for (int j = 0; j < 4; ++j) acc[i][j] = (floatx4){0.f, 0.f, 0.f, 0.f};

  for (int kt = 0; kt < Hc; kt += 64) {
    half8 va0 = *(const half8*)(gA0 + kt);
    half8 va1 = *(const half8*)(gA0 + kt + 32);
    half8 va2 = *(const half8*)(gA1 + kt);
    half8 va3 = *(const half8*)(gA1 + kt + 32);
    half8 vb[4];
#pragma unroll
    for (int fg = 0; fg < 4; ++fg) {
      const float* gb = (fg >> 1) ? gB1 : gB0;
      int kbase = j0 + kt + (fg & 1) * 32 + lq * 8;
#pragma unroll
      for (int j = 0; j < 8; ++j)
        vb[fg][j] = (half_t)gb[(size_t)(kbase + j) * DIM];
    }
    __syncthreads();
    *(half8*)(ldsA + (4 * w + 0) * 512 + l * 8) = va0;
    *(half8*)(ldsA + (4 * w + 1) * 512 + l * 8) = va1;
    *(half8*)(ldsA + (4 * w + 2) * 512 + l * 8) = va2;
    *(half8*)(ldsA + (4 * w + 3) * 512 + l * 8) = va3;
    *(half8*)(ldsB + (4 * w + 0) * 512 + l * 8) = vb[0];
    *(half8*)(ldsB + (4 * w + 1) * 512 + l * 8) = vb[1];
    *(half8*)(ldsB + (4 * w + 2) * 512 + l * 8) = vb[2];
    *(half8*)(ldsB + (4 * w + 3) * 512 + l * 8) = vb[3];
    __syncthreads();
#pragma unroll
    for (int ks = 0; ks < 2; ++ks) {
      half8 a[4], b[4];
#pragma unroll
      for (int i = 0; i < 4; ++i)
        a[i] = *(const half8*)(ldsA + ((4 * wr + i) * 2 + ks) * 512 + l * 8);
#pragma unroll
      for (int j = 0; j < 4; ++j)
        b[j] = *(const half8*)(ldsB + ((4 * wc + j) * 2 + ks) * 512 + l * 8);
#pragma unroll
      for (int i = 0; i < 4; ++i)
#pragma unroll
        for (int j = 0; j < 4; ++j)
          acc[i][j] = __builtin_amdgcn_mfma_f32_16x16x32_f16(a[i], b[j], acc[i][j], 0, 0, 0);
    }
  }

#pragma unroll
  for (int i = 0; i < 4; ++i)
#pragma unroll
    for (int r = 0; r < 4; ++r) {
      int row = (4 * wr + i) * 16 + lq * 4 + r;
      float wt = pair_wt[p0 + row];
      if (wt != 0.0f) {
        int tok = pair_tok[p0 + row];
        float* op = out + (size_t)tok * DIM + jt;
#pragma unroll
        for (int j = 0; j < 4; ++j) {
          int coll = (4 * wc + j) * 16 + lr;
          unsafeAtomicAdd(op + coll, wt * acc[i][j][r]);
        }
      }
    }
}

// ---------------------------------------------------------------- launch
extern "C" void kernel_launch(void* const* d_in, const int* in_sizes, int n_in,
                              void* d_out, int out_size, void* d_ws, size_t ws_size,
                              hipStream_t stream) {
  const float* x  = (const float*)d_in[0];
  const float* Wg = (const float*)d_in[1];
  const float* W1 = (const float*)d_in[2];
  const float* b1 = (const float*)d_in[3];
  const float* W2 = (const float*)d_in[4];
  const float* b2 = (const float*)d_in[5];
  float* out = (float*)d_out;

  char* p = (char*)d_ws;
  auto alloc = [&](size_t bytes) -> char* {
    char* r = p; p += (bytes + 255) & ~(size_t)255; return r;
  };
  int*      top_i    = (int*)     alloc((size_t)T_TOK * 2 * sizeof(int));
  float*    top_w    = (float*)   alloc((size_t)T_TOK * 2 * sizeof(float));
  float*    prob_sum = (float*)   alloc(NE * sizeof(float));
  unsigned* cnt      = (unsigned*)alloc(NE * sizeof(unsigned));
  int*      pad_off  = (int*)     alloc((NE + 1) * sizeof(int));
  int*      ptotal   = (int*)     alloc(sizeof(int));
  unsigned* cursor   = (unsigned*)alloc(NE * sizeof(unsigned));
  int*      pair_tok = (int*)     alloc(PADMAX * sizeof(int));
  float*    pair_wt  = (float*)   alloc(PADMAX * sizeof(float));

  size_t used  = (size_t)(p - (char*)d_ws);          // ~140 KB fixed
  size_t avail = ws_size > used ? ws_size - used : 0;

  // Mode A per-H-column cost: W1t + W2t (2*NE*DIM*2B) + hbuf (PADMAX*2B) = 51200 B
  size_t per_col_a = (size_t)2 * NE * DIM * sizeof(half_t) + (size_t)PADMAX * sizeof(half_t);
  int HcA = (int)((avail / per_col_a) & ~(size_t)127);
  if (HcA > HID) HcA = HID;
  bool modeA = (HcA >= 128);

  k_reset<<<dim3((PADMAX + 255) / 256), 256, 0, stream>>>(prob_sum, cnt, cursor, pair_tok, pair_wt);
  k_router<<<dim3(T_TOK / 16), 256, 0, stream>>>(x, Wg, top_i, top_w, prob_sum, cnt);
  k_scan<<<1, 64, 0, stream>>>(cnt, prob_sum, pad_off, ptotal, out + (size_t)T_TOK * DIM);
  k_scatter<<<dim3(T_TOK / 256), 256, 0, stream>>>(top_i, top_w, pad_off, cursor, pair_tok, pair_wt);
  k_init_out<<<dim3((size_t)T_TOK * DIM / 256), 256, 0, stream>>>(top_i, top_w, b2, out);

  if (modeA) {
    int Hc = HcA;
    half_t* W1t  = (half_t*)alloc((size_t)NE * Hc * DIM * sizeof(half_t));
    half_t* W2t  = (half_t*)alloc((size_t)NE * DIM * Hc * sizeof(half_t));
    half_t* hbuf = (half_t*)alloc((size_t)PADMAX * Hc * sizeof(half_t));
    for (int jb = 0; jb < HID; jb += Hc) {
      int hc = (HID - jb) < Hc ? (HID - jb) : Hc;   // multiple of 128
      k_tr_w1<<<dim3(hc / 64, DIM / 64, NE), 256, 0, stream>>>(W1, W1t, jb, hc);
      k_gemm1_a<<<dim3(hc / 128, PADMAX / 128), 256, 0, stream>>>(
          x, W1t, b1, pair_tok, pad_off, ptotal, hbuf, jb, hc);
      k_tr_w2<<<dim3(DIM / 64, hc / 64, NE), 256, 0, stream>>>(W2, W2t, jb, hc);
      k_gemm2_a<<<dim3(DIM / 128, PADMAX / 128), 256, 0, stream>>>(
          hbuf, W2t, pair_tok, pair_wt, pad_off, ptotal, out, hc);
    }
  } else {
    // Mode B: only hbuf, fp32 weights read directly in the GEMMs.
    int Hc = (int)((avail / ((size_t)PADMAX * sizeof(half_t))) & ~(size_t)127);
    if (Hc > HID) Hc = HID;
    if (Hc < 128) Hc = 128;   // ~2.4 MB floor (R1 passed with this footprint)
    half_t* hbuf = (half_t*)alloc((size_t)PADMAX * Hc * sizeof(half_t));
    for (int jb = 0; jb < HID; jb += Hc) {
      int hc = (HID - jb) < Hc ? (HID - jb) : Hc;
      k_gemm1_b<<<dim3(hc / 128, PADMAX / 128), 256, 0, stream>>>(
          x, W1, b1, pair_tok, pad_off, ptotal, hbuf, jb, hc);
      k_gemm2_b<<<dim3(DIM / 128, PADMAX / 128), 256, 0, stream>>>(
          hbuf, W2, pair_tok, pair_wt, pad_off, ptotal, out, jb, hc);
    }
  }
}